// Round 6
// baseline (365.656 us; speedup 1.0000x reference)
//
#include <hip/hip_runtime.h>
#include <stdint.h>

// Problem constants
#define T_TOK 4096
#define H_DIM 4096
#define I_DIM 1408
#define E_NUM 16
#define TPE   256

typedef __attribute__((ext_vector_type(4))) int   i32x4;
typedef __attribute__((ext_vector_type(4))) float f32x4;

// async global->LDS, 16B/lane. LDS dest is WAVE-UNIFORM base; HW writes
// base + lane*16. Global src is per-lane (so we pre-swizzle the source).
__device__ __forceinline__ void gload16(const void* g, void* l) {
  __builtin_amdgcn_global_load_lds(
      (const __attribute__((address_space(1))) void*)g,
      (__attribute__((address_space(3))) void*)l, 16, 0, 0);
}

// ---------------------------------------------------------------------------
// Kernel 1: dynamic per-token quant of x (f32 -> int8 + scale). 1 block/token.
// ---------------------------------------------------------------------------
__global__ __launch_bounds__(256)
void quant_x_kernel(const float* __restrict__ x,
                    int8_t* __restrict__ xq,
                    float* __restrict__ s1) {
  const int t   = blockIdx.x;
  const int tid = threadIdx.x;
  const float* row = x + (size_t)t * H_DIM;

  f32x4 v[4];
  float mx = 0.0f;
#pragma unroll
  for (int i = 0; i < 4; ++i) {
    v[i] = *(const f32x4*)(row + (size_t)(i * 256 + tid) * 4);
#pragma unroll
    for (int j = 0; j < 4; ++j) mx = fmaxf(mx, fabsf(v[i][j]));
  }
#pragma unroll
  for (int off = 32; off > 0; off >>= 1) mx = fmaxf(mx, __shfl_xor(mx, off));
  __shared__ float wmax[4];
  if ((tid & 63) == 0) wmax[tid >> 6] = mx;
  __syncthreads();
  float s = fmaxf(fmaxf(wmax[0], wmax[1]), fmaxf(wmax[2], wmax[3])) / 127.0f;
  s = fmaxf(s, 1e-30f);

  int* orow = (int*)(xq + (size_t)t * H_DIM);
#pragma unroll
  for (int i = 0; i < 4; ++i) {
    int packed = 0;
#pragma unroll
    for (int j = 0; j < 4; ++j) {
      float q = rintf(v[i][j] / s);              // rintf = half-even = jnp.round
      q = fminf(fmaxf(q, -128.0f), 127.0f);
      packed |= ((int)q & 0xff) << (8 * j);
    }
    orow[i * 256 + tid] = packed;
  }
  if (tid == 0) s1[t] = s;
}

// ---------------------------------------------------------------------------
// Kernel 3: h = silu(gate)*up*smooth; per-token quant -> hq, s2. 1 block/token.
// ---------------------------------------------------------------------------
__global__ __launch_bounds__(256)
void act_quant_kernel(const float* __restrict__ y,
                      const float* __restrict__ smooth,
                      int8_t* __restrict__ hq,
                      float* __restrict__ s2) {
  const int t   = blockIdx.x;
  const int e   = t >> 8;               // TPE = 256
  const int tid = threadIdx.x;
  const float* gate = y + (size_t)t * (2 * I_DIM);
  const float* up   = gate + I_DIM;
  const float* ss   = smooth + (size_t)e * I_DIM;

  float h[6];
  float mx = 0.0f;
#pragma unroll
  for (int i = 0; i < 6; ++i) {
    const int idx = tid + i * 256;
    h[i] = 0.0f;
    if (idx < I_DIM) {
      const float g = gate[idx];
      const float u = up[idx];
      const float sig = 1.0f / (1.0f + expf(-g));
      h[i] = ((g * sig) * u) * ss[idx];
      mx = fmaxf(mx, fabsf(h[i]));
    }
  }
#pragma unroll
  for (int off = 32; off > 0; off >>= 1) mx = fmaxf(mx, __shfl_xor(mx, off));
  __shared__ float wmax[4];
  if ((tid & 63) == 0) wmax[tid >> 6] = mx;
  __syncthreads();
  float s = fmaxf(fmaxf(wmax[0], wmax[1]), fmaxf(wmax[2], wmax[3])) / 127.0f;
  s = fmaxf(s, 1e-30f);

  int8_t* orow = hq + (size_t)t * I_DIM;
#pragma unroll
  for (int i = 0; i < 6; ++i) {
    const int idx = tid + i * 256;
    if (idx < I_DIM) {
      float q = rintf(h[i] / s);
      q = fminf(fmaxf(q, -128.0f), 127.0f);
      orow[idx] = (int8_t)(int)q;
    }
  }
  if (tid == 0) s2[t] = s;
}

// ---------------------------------------------------------------------------
// Grouped int8 GEMM, weights arrive as INT32 (harness passes ints as int*).
//   A: (E*TPE, K) int8 row-major (our own quant output)
//   B32: (E, N, K) int32, values in [-127,127] -> truncate low byte on the fly
//   C[t,n] = ((f32)sum_k A[t,k]*B[e,n,k] * scaleN[e,n]) * scaleM[t]
// Block tile: M=256 (whole expert) x N=128, BK=64. 512 thr = 8 waves (4Mx2N),
// each wave 64x64 (4x4 frags of mfma_i32_16x16x64_i8).
// A: global_load_lds(16B), linear LDS dest + XOR-preswizzled global source.
// B: reg-staged (dwordx4 -> byte-pack -> ds_write_b128 at swizzled addr).
// Swizzle (both sides, same involution): LDS(row,blk) = global(row, blk^(row&3)).
// Weight bytes are read exactly ONCE per call (M covers all TPE tokens).
// ---------------------------------------------------------------------------
template <int N, int K>
__global__ __launch_bounds__(512)
void gemm_i8_w32_kernel(const int8_t* __restrict__ A,
                        const int* __restrict__ B32,
                        float* __restrict__ C,
                        const float* __restrict__ scaleN,
                        const float* __restrict__ scaleM) {
  constexpr int NT = K / 64;
  __shared__ __align__(16) int8_t As[2][256 * 64];   // 16 KB each
  __shared__ __align__(16) int8_t Bs[2][128 * 64];   //  8 KB each

  const int bn   = blockIdx.x;
  const int e    = blockIdx.y;
  const int tid  = threadIdx.x;
  const int lane = tid & 63;
  const int wid  = tid >> 6;          // 0..7
  const int wm   = wid >> 1;          // 0..3  (64-row quadrant of 256)
  const int wn   = wid & 1;           // 0..1  (64-col half of 128)

  const int8_t* Abase = A + (size_t)e * TPE * K;
  const int*    Bbase = B32 + ((size_t)e * N + (size_t)bn * 128) * (size_t)K;

  // --- A staging addresses (2 chunks of 128 rows; 16B per lane) ---
  const int arow0 = wid * 16 + (lane >> 2);           // 0..127
  const int ablk  = lane & 3;
  const int8_t* gA0 = Abase + (size_t)arow0 * K + ((ablk ^ (arow0 & 3)) << 4);
  const int arow1 = 128 + arow0;
  const int8_t* gA1 = Abase + (size_t)arow1 * K + ((ablk ^ (arow1 & 3)) << 4);

  // --- B staging addresses (one 16B chunk per thread: 128 rows x 4 blks) ---
  const int brow = tid >> 2;                          // 0..127
  const int bblk = tid & 3;
  const int* gB = Bbase + (size_t)brow * K + (bblk << 4);   // int units
  const int bldsOff = brow * 64 + ((bblk ^ (brow & 3)) << 4);

  // --- MFMA fragment LDS read offsets (same XOR on read) ---
  const int r15 = lane & 15;
  const int kg  = lane >> 4;
  int aoff[4], boff[4];
#pragma unroll
  for (int m = 0; m < 4; ++m) {
    const int r = wm * 64 + m * 16 + r15;             // 0..255
    aoff[m] = r * 64 + ((kg ^ (r & 3)) << 4);
  }
#pragma unroll
  for (int n = 0; n < 4; ++n) {
    const int r = wn * 64 + n * 16 + r15;             // 0..127
    boff[n] = r * 64 + ((kg ^ (r & 3)) << 4);
  }

  i32x4 acc[4][4] = {};

  // --- prologue: stage K-tile 0 into buffer 0 ---
  gload16(gA0, &As[0][wid * 1024]);
  gload16(gA1, &As[0][8192 + wid * 1024]);
  {
    i32x4 b0 = *(const i32x4*)(gB + 0);
    i32x4 b1 = *(const i32x4*)(gB + 4);
    i32x4 b2 = *(const i32x4*)(gB + 8);
    i32x4 b3 = *(const i32x4*)(gB + 12);
    i32x4 pk;
    pk[0] = (b0[0] & 255) | ((b0[1] & 255) << 8) | ((b0[2] & 255) << 16) | (b0[3] << 24);
    pk[1] = (b1[0] & 255) | ((b1[1] & 255) << 8) | ((b1[2] & 255) << 16) | (b1[3] << 24);
    pk[2] = (b2[0] & 255) | ((b2[1] & 255) << 8) | ((b2[2] & 255) << 16) | (b2[3] << 24);
    pk[3] = (b3[0] & 255) | ((b3[1] & 255) << 8) | ((b3[2] & 255) << 16) | (b3[3] << 24);
    *(i32x4*)(&Bs[0][bldsOff]) = pk;
  }
  __syncthreads();  // compiler drains vmcnt+lgkmcnt before barrier

  for (int kt = 0; kt < NT; ++kt) {
    const int buf = kt & 1;
    const bool more = (kt + 1) < NT;
    i32x4 n0, n1, n2, n3;
    if (more) {  // issue next-tile loads first: A async->LDS, B -> regs
      const size_t ko = (size_t)(kt + 1) * 64;
      gload16(gA0 + ko, &As[buf ^ 1][wid * 1024]);
      gload16(gA1 + ko, &As[buf ^ 1][8192 + wid * 1024]);
      const int* g = gB + (kt + 1) * 64;
      n0 = *(const i32x4*)(g + 0);
      n1 = *(const i32x4*)(g + 4);
      n2 = *(const i32x4*)(g + 8);
      n3 = *(const i32x4*)(g + 12);
    }
    // compute on current buffer
    i32x4 av[4], bv[4];
#pragma unroll
    for (int m = 0; m < 4; ++m) av[m] = *(const i32x4*)(&As[buf][aoff[m]]);
#pragma unroll
    for (int n = 0; n < 4; ++n) bv[n] = *(const i32x4*)(&Bs[buf][boff[n]]);
#pragma unroll
    for (int m = 0; m < 4; ++m)
#pragma unroll
      for (int n = 0; n < 4; ++n)
        acc[m][n] = __builtin_amdgcn_mfma_i32_16x16x64_i8(av[m], bv[n], acc[m][n], 0, 0, 0);
    if (more) {  // pack + swizzled write into next buffer (vmcnt wait lands here)
      i32x4 pk;
      pk[0] = (n0[0] & 255) | ((n0[1] & 255) << 8) | ((n0[2] & 255) << 16) | (n0[3] << 24);
      pk[1] = (n1[0] & 255) | ((n1[1] & 255) << 8) | ((n1[2] & 255) << 16) | (n1[3] << 24);
      pk[2] = (n2[0] & 255) | ((n2[1] & 255) << 8) | ((n2[2] & 255) << 16) | (n2[3] << 24);
      pk[3] = (n3[0] & 255) | ((n3[1] & 255) << 8) | ((n3[2] & 255) << 16) | (n3[3] << 24);
      *(i32x4*)(&Bs[buf ^ 1][bldsOff]) = pk;
    }
    __syncthreads();
  }

  // --- epilogue: C/D layout col = lane&15, row = (lane>>4)*4 + reg ---
  const float* sN = scaleN + (size_t)e * N + (size_t)bn * 128;
  const float* sM = scaleM + e * TPE;
  float* Cbase = C + (size_t)e * TPE * N + (size_t)bn * 128;
#pragma unroll
  for (int m = 0; m < 4; ++m) {
#pragma unroll
    for (int j = 0; j < 4; ++j) {
      const int row = wm * 64 + m * 16 + kg * 4 + j;   // token row 0..255
      const float smv = sM[row];
      float* cr = Cbase + (size_t)row * N;
#pragma unroll
      for (int n = 0; n < 4; ++n) {
        const int col = wn * 64 + n * 16 + r15;
        cr[col] = ((float)acc[m][n][j] * sN[col]) * smv;  // ref mult order
      }
    }
  }
}

// ---------------------------------------------------------------------------
extern "C" void kernel_launch(void* const* d_in, const int* in_sizes, int n_in,
                              void* d_out, int out_size, void* d_ws, size_t ws_size,
                              hipStream_t stream) {
  const float* x         = (const float*)d_in[0];
  const int*   w13       = (const int*)d_in[1];   // int8 values, int32 storage
  const int*   w2        = (const int*)d_in[2];   // int8 values, int32 storage
  const float* w13_scale = (const float*)d_in[3];
  const float* smooth    = (const float*)d_in[4];
  const float* w2_scale  = (const float*)d_in[5];
  // d_in[6] expert_tokens: unused (uniform TPE per expert by construction)

  uint8_t* ws = (uint8_t*)d_ws;
  int8_t* xq = (int8_t*)ws;                        // 16,777,216 B
  int8_t* hq = (int8_t*)ws;                        // 5,767,168 B (overlay: xq dead after gemm1)
  float*  s1 = (float*)(ws + 16777216);            // 16,384 B
  float*  s2 = (float*)(ws + 16777216 + 16384);    // 16,384 B
  float*  y  = (float*)(ws + 16777216 + 32768);    // 46,137,344 B  (total ~63 MB)

  float* out = (float*)d_out;

  quant_x_kernel<<<dim3(T_TOK), dim3(256), 0, stream>>>(x, xq, s1);

  // GEMM1: A=xq (4096,4096), B=w13 (16,2816,4096) -> y (4096,2816)
  gemm_i8_w32_kernel<2 * I_DIM, H_DIM>
      <<<dim3((2 * I_DIM) / 128, E_NUM), dim3(512), 0, stream>>>(
          xq, w13, y, w13_scale, s1);

  act_quant_kernel<<<dim3(T_TOK), dim3(256), 0, stream>>>(y, smooth, hq, s2);

  // GEMM2: A=hq (4096,1408), B=w2 (16,4096,1408) -> out (4096,4096)
  gemm_i8_w32_kernel<H_DIM, I_DIM>
      <<<dim3(H_DIM / 128, E_NUM), dim3(512), 0, stream>>>(
          hq, w2, out, w2_scale, s2);
}

// Round 7
// 348.269 us; speedup vs baseline: 1.0499x; 1.0499x over previous
//
#include <hip/hip_runtime.h>
#include <stdint.h>

// Problem constants
#define T_TOK 4096
#define H_DIM 4096
#define I_DIM 1408
#define E_NUM 16
#define TPE   256

typedef __attribute__((ext_vector_type(4))) int   i32x4;
typedef __attribute__((ext_vector_type(4))) float f32x4;

// async global->LDS, 16B/lane. LDS dest is WAVE-UNIFORM base; HW writes
// base + lane*16. Global src is per-lane (so we pre-swizzle the source).
__device__ __forceinline__ void gload16(const void* g, void* l) {
  __builtin_amdgcn_global_load_lds(
      (const __attribute__((address_space(1))) void*)g,
      (__attribute__((address_space(3))) void*)l, 16, 0, 0);
}

// swizzle key: involution on the 4 16B-blocks of a 64B LDS row; incorporates
// row bits 0-3 so rows 4 apart land on different banks (conflict-free b128).
__device__ __forceinline__ int fswz(int r) { return (r ^ (r >> 2)) & 3; }

// ---------------------------------------------------------------------------
// Kernel 1: dynamic per-token quant of x (f32 -> int8 + scale). 1 block/token.
// ---------------------------------------------------------------------------
__global__ __launch_bounds__(256)
void quant_x_kernel(const float* __restrict__ x,
                    int8_t* __restrict__ xq,
                    float* __restrict__ s1) {
  const int t   = blockIdx.x;
  const int tid = threadIdx.x;
  const float* row = x + (size_t)t * H_DIM;

  f32x4 v[4];
  float mx = 0.0f;
#pragma unroll
  for (int i = 0; i < 4; ++i) {
    v[i] = *(const f32x4*)(row + (size_t)(i * 256 + tid) * 4);
#pragma unroll
    for (int j = 0; j < 4; ++j) mx = fmaxf(mx, fabsf(v[i][j]));
  }
#pragma unroll
  for (int off = 32; off > 0; off >>= 1) mx = fmaxf(mx, __shfl_xor(mx, off));
  __shared__ float wmax[4];
  if ((tid & 63) == 0) wmax[tid >> 6] = mx;
  __syncthreads();
  float s = fmaxf(fmaxf(wmax[0], wmax[1]), fmaxf(wmax[2], wmax[3])) / 127.0f;
  s = fmaxf(s, 1e-30f);

  int* orow = (int*)(xq + (size_t)t * H_DIM);
#pragma unroll
  for (int i = 0; i < 4; ++i) {
    int packed = 0;
#pragma unroll
    for (int j = 0; j < 4; ++j) {
      float q = rintf(v[i][j] / s);              // rintf = half-even = jnp.round
      q = fminf(fmaxf(q, -128.0f), 127.0f);
      packed |= ((int)q & 0xff) << (8 * j);
    }
    orow[i * 256 + tid] = packed;
  }
  if (tid == 0) s1[t] = s;
}

// ---------------------------------------------------------------------------
// Kernel 3: h = silu(gate)*up*smooth; per-token quant -> hq, s2. 1 block/token.
// Vectorized: 352 f32x4 per row (I=1408), packed int8x4 stores.
// ---------------------------------------------------------------------------
__global__ __launch_bounds__(256)
void act_quant_kernel(const float* __restrict__ y,
                      const float* __restrict__ smooth,
                      int8_t* __restrict__ hq,
                      float* __restrict__ s2) {
  const int t   = blockIdx.x;
  const int e   = t >> 8;               // TPE = 256
  const int tid = threadIdx.x;
  const float* gate = y + (size_t)t * (2 * I_DIM);
  const float* up   = gate + I_DIM;
  const float* ss   = smooth + (size_t)e * I_DIM;
  constexpr int NV = I_DIM / 4;          // 352 vec4 per row

  f32x4 h[2];
  float mx = 0.0f;
#pragma unroll
  for (int i = 0; i < 2; ++i) {
    const int idx = tid + i * 256;
    h[i] = (f32x4)(0.0f);
    if (idx < NV) {
      const f32x4 g4 = *(const f32x4*)(gate + idx * 4);
      const f32x4 u4 = *(const f32x4*)(up + idx * 4);
      const f32x4 s4 = *(const f32x4*)(ss + idx * 4);
#pragma unroll
      for (int j = 0; j < 4; ++j) {
        const float g = g4[j];
        const float sig = 1.0f / (1.0f + expf(-g));
        h[i][j] = ((g * sig) * u4[j]) * s4[j];
        mx = fmaxf(mx, fabsf(h[i][j]));
      }
    }
  }
#pragma unroll
  for (int off = 32; off > 0; off >>= 1) mx = fmaxf(mx, __shfl_xor(mx, off));
  __shared__ float wmax[4];
  if ((tid & 63) == 0) wmax[tid >> 6] = mx;
  __syncthreads();
  float s = fmaxf(fmaxf(wmax[0], wmax[1]), fmaxf(wmax[2], wmax[3])) / 127.0f;
  s = fmaxf(s, 1e-30f);

  int* orow = (int*)(hq + (size_t)t * I_DIM);   // 1408 % 16 == 0, aligned
#pragma unroll
  for (int i = 0; i < 2; ++i) {
    const int idx = tid + i * 256;
    if (idx < NV) {
      int packed = 0;
#pragma unroll
      for (int j = 0; j < 4; ++j) {
        float q = rintf(h[i][j] / s);
        q = fminf(fmaxf(q, -128.0f), 127.0f);
        packed |= ((int)q & 0xff) << (8 * j);
      }
      orow[idx] = packed;
    }
  }
  if (tid == 0) s2[t] = s;
}

// ---------------------------------------------------------------------------
// Grouped int8 GEMM, weights arrive as INT32 (harness passes ints as int*).
//   A: (E*TPE, K) int8 row-major (our own quant output)
//   B32: (E, N, K) int32, values in [-127,127] -> truncate low byte on the fly
//   C[t,n] = ((f32)sum_k A[t,k]*B[e,n,k] * scaleN[e,n]) * scaleM[t]
// Block tile: M=256 (whole expert: weight bytes read ONCE) x N=64, BK=64.
// 512 thr = 8 waves (4M x 2N); wave = 64x32 = 4x2 frags of mfma_i32_16x16x64_i8.
// LDS 40KB (dbuf) -> 2 blocks/CU co-resident with __launch_bounds__(512,4):
// one block's MFMA/barrier phase overlaps the other's load burst (keeps HBM
// request queue full -> BW-bound saturation).
// A: global_load_lds(16B), linear LDS dest + XOR-preswizzled global source.
// B: reg-staged by waves 0-3 (dwordx4 x4 -> byte-pack -> swizzled ds_write_b128).
// Swizzle (both sides, same involution): LDS(row,blk) = global(row, blk^fswz(row)).
// ---------------------------------------------------------------------------
template <int N, int K>
__global__ __launch_bounds__(512, 4)
void gemm_i8_w32_kernel(const int8_t* __restrict__ A,
                        const int* __restrict__ B32,
                        float* __restrict__ C,
                        const float* __restrict__ scaleN,
                        const float* __restrict__ scaleM) {
  constexpr int NT = K / 64;
  __shared__ __align__(16) int8_t As[2][256 * 64];   // 16 KB each
  __shared__ __align__(16) int8_t Bs[2][64 * 64];    //  4 KB each

  const int bn   = blockIdx.x;
  const int e    = blockIdx.y;
  const int tid  = threadIdx.x;
  const int lane = tid & 63;
  const int wid  = tid >> 6;          // 0..7
  const int wm   = wid >> 1;          // 0..3  (64-row quadrant of 256)
  const int wn   = wid & 1;           // 0..1  (32-col half of 64)

  const int8_t* Abase = A + (size_t)e * TPE * K;
  const int*    Bbase = B32 + ((size_t)e * N + (size_t)bn * 64) * (size_t)K;

  // --- A staging addresses (2 chunks of 128 rows; 16B per lane) ---
  const int arow0 = wid * 16 + (lane >> 2);           // 0..127
  const int ablk  = lane & 3;
  const int8_t* gA0 = Abase + (size_t)arow0 * K + ((ablk ^ fswz(arow0)) << 4);
  const int arow1 = 128 + arow0;
  const int8_t* gA1 = Abase + (size_t)arow1 * K + ((ablk ^ fswz(arow1)) << 4);

  // --- B staging (waves 0-3 only): one 16B chunk per thread (64 rows x 4 blks)
  const int brow = (tid & 255) >> 2;                  // 0..63
  const int bblk = tid & 3;
  const int* gB = Bbase + (size_t)brow * K + (bblk << 4);   // int units
  const int bldsOff = brow * 64 + ((bblk ^ fswz(brow)) << 4);
  const bool doB = (tid < 256);

  // --- MFMA fragment LDS read offsets (same XOR on read) ---
  const int r15 = lane & 15;
  const int kg  = lane >> 4;
  int aoff[4], boff[2];
#pragma unroll
  for (int m = 0; m < 4; ++m) {
    const int r = wm * 64 + m * 16 + r15;             // 0..255
    aoff[m] = r * 64 + ((kg ^ fswz(r)) << 4);
  }
#pragma unroll
  for (int n = 0; n < 2; ++n) {
    const int r = wn * 32 + n * 16 + r15;             // 0..63
    boff[n] = r * 64 + ((kg ^ fswz(r)) << 4);
  }

  i32x4 acc[4][2] = {};

  // --- prologue: stage K-tile 0 into buffer 0 ---
  gload16(gA0, &As[0][wid * 1024]);
  gload16(gA1, &As[0][8192 + wid * 1024]);
  if (doB) {
    i32x4 b0 = *(const i32x4*)(gB + 0);
    i32x4 b1 = *(const i32x4*)(gB + 4);
    i32x4 b2 = *(const i32x4*)(gB + 8);
    i32x4 b3 = *(const i32x4*)(gB + 12);
    i32x4 pk;
    pk[0] = (b0[0] & 255) | ((b0[1] & 255) << 8) | ((b0[2] & 255) << 16) | (b0[3] << 24);
    pk[1] = (b1[0] & 255) | ((b1[1] & 255) << 8) | ((b1[2] & 255) << 16) | (b1[3] << 24);
    pk[2] = (b2[0] & 255) | ((b2[1] & 255) << 8) | ((b2[2] & 255) << 16) | (b2[3] << 24);
    pk[3] = (b3[0] & 255) | ((b3[1] & 255) << 8) | ((b3[2] & 255) << 16) | (b3[3] << 24);
    *(i32x4*)(&Bs[0][bldsOff]) = pk;
  }
  __syncthreads();  // compiler drains vmcnt+lgkmcnt before barrier

  for (int kt = 0; kt < NT; ++kt) {
    const int buf = kt & 1;
    const bool more = (kt + 1) < NT;
    i32x4 n0, n1, n2, n3;
    if (more) {  // issue next-tile loads first: A async->LDS, B -> regs
      const size_t ko = (size_t)(kt + 1) * 64;
      gload16(gA0 + ko, &As[buf ^ 1][wid * 1024]);
      gload16(gA1 + ko, &As[buf ^ 1][8192 + wid * 1024]);
      if (doB) {
        const int* g = gB + (kt + 1) * 64;
        n0 = *(const i32x4*)(g + 0);
        n1 = *(const i32x4*)(g + 4);
        n2 = *(const i32x4*)(g + 8);
        n3 = *(const i32x4*)(g + 12);
      }
    }
    // compute on current buffer
    i32x4 av[4], bv[2];
#pragma unroll
    for (int m = 0; m < 4; ++m) av[m] = *(const i32x4*)(&As[buf][aoff[m]]);
#pragma unroll
    for (int n = 0; n < 2; ++n) bv[n] = *(const i32x4*)(&Bs[buf][boff[n]]);
#pragma unroll
    for (int m = 0; m < 4; ++m)
#pragma unroll
      for (int n = 0; n < 2; ++n)
        acc[m][n] = __builtin_amdgcn_mfma_i32_16x16x64_i8(av[m], bv[n], acc[m][n], 0, 0, 0);
    if (more && doB) {  // pack + swizzled write into next buffer
      i32x4 pk;
      pk[0] = (n0[0] & 255) | ((n0[1] & 255) << 8) | ((n0[2] & 255) << 16) | (n0[3] << 24);
      pk[1] = (n1[0] & 255) | ((n1[1] & 255) << 8) | ((n1[2] & 255) << 16) | (n1[3] << 24);
      pk[2] = (n2[0] & 255) | ((n2[1] & 255) << 8) | ((n2[2] & 255) << 16) | (n2[3] << 24);
      pk[3] = (n3[0] & 255) | ((n3[1] & 255) << 8) | ((n3[2] & 255) << 16) | (n3[3] << 24);
      *(i32x4*)(&Bs[buf ^ 1][bldsOff]) = pk;
    }
    __syncthreads();
  }

  // --- epilogue: C/D layout col = lane&15, row = (lane>>4)*4 + reg ---
  const float* sN = scaleN + (size_t)e * N + (size_t)bn * 64;
  const float* sM = scaleM + e * TPE;
  float* Cbase = C + (size_t)e * TPE * N + (size_t)bn * 64;
#pragma unroll
  for (int m = 0; m < 4; ++m) {
#pragma unroll
    for (int j = 0; j < 4; ++j) {
      const int row = wm * 64 + m * 16 + kg * 4 + j;   // token row 0..255
      const float smv = sM[row];
      float* cr = Cbase + (size_t)row * N;
#pragma unroll
      for (int n = 0; n < 2; ++n) {
        const int col = wn * 32 + n * 16 + r15;
        cr[col] = ((float)acc[m][n][j] * sN[col]) * smv;  // ref mult order
      }
    }
  }
}

// ---------------------------------------------------------------------------
extern "C" void kernel_launch(void* const* d_in, const int* in_sizes, int n_in,
                              void* d_out, int out_size, void* d_ws, size_t ws_size,
                              hipStream_t stream) {
  const float* x         = (const float*)d_in[0];
  const int*   w13       = (const int*)d_in[1];   // int8 values, int32 storage
  const int*   w2        = (const int*)d_in[2];   // int8 values, int32 storage
  const float* w13_scale = (const float*)d_in[3];
  const float* smooth    = (const float*)d_in[4];
  const float* w2_scale  = (const float*)d_in[5];
  // d_in[6] expert_tokens: unused (uniform TPE per expert by construction)

  uint8_t* ws = (uint8_t*)d_ws;
  int8_t* xq = (int8_t*)ws;                        // 16,777,216 B
  int8_t* hq = (int8_t*)ws;                        // 5,767,168 B (overlay: xq dead after gemm1)
  float*  s1 = (float*)(ws + 16777216);            // 16,384 B
  float*  s2 = (float*)(ws + 16777216 + 16384);    // 16,384 B
  float*  y  = (float*)(ws + 16777216 + 32768);    // 46,137,344 B  (total ~63 MB)

  float* out = (float*)d_out;

  quant_x_kernel<<<dim3(T_TOK), dim3(256), 0, stream>>>(x, xq, s1);

  // GEMM1: A=xq (4096,4096), B=w13 (16,2816,4096) -> y (4096,2816)
  gemm_i8_w32_kernel<2 * I_DIM, H_DIM>
      <<<dim3((2 * I_DIM) / 64, E_NUM), dim3(512), 0, stream>>>(
          xq, w13, y, w13_scale, s1);

  act_quant_kernel<<<dim3(T_TOK), dim3(256), 0, stream>>>(y, smooth, hq, s2);

  // GEMM2: A=hq (4096,1408), B=w2 (16,4096,1408) -> out (4096,4096)
  gemm_i8_w32_kernel<H_DIM, I_DIM>
      <<<dim3(H_DIM / 64, E_NUM), dim3(512), 0, stream>>>(
          hq, w2, out, w2_scale, s2);
}